// Round 4
// baseline (473.415 us; speedup 1.0000x reference)
//
#include <hip/hip_runtime.h>
#include <hip/hip_bf16.h>
#include <cstdint>

#define DEV __device__ __forceinline__

typedef __attribute__((ext_vector_type(8))) short bf16x8;
typedef __attribute__((ext_vector_type(4))) float f32x4;

static constexpr int B_ = 2, T_ = 2048, D_ = 512, H_ = 8;

DEV ushort f2bf(float f) {
  union { float f; uint32_t u; } c; c.f = f;
  uint32_t u = c.u + 0x7fffu + ((c.u >> 16) & 1u);
  return (ushort)(u >> 16);
}
DEV float bf2f(ushort h) {
  union { uint32_t u; float f; } c; c.u = ((uint32_t)h) << 16; return c.f;
}

// fp32 -> bf16 (n % 4 == 0)
__global__ void cvt_bf16_k(const float* __restrict__ in, ushort* __restrict__ out, int n) {
  int stride = gridDim.x * blockDim.x;
  for (int i = blockIdx.x * blockDim.x + threadIdx.x; i * 4 < n; i += stride) {
    float4 f = reinterpret_cast<const float4*>(in)[i];
    ushort4 o;
    o.x = f2bf(f.x); o.y = f2bf(f.y); o.z = f2bf(f.z); o.w = f2bf(f.w);
    reinterpret_cast<ushort4*>(out)[i] = o;
  }
}

__global__ void zfill_k(float* __restrict__ p, int n) {  // n % 4 == 0
  int stride = gridDim.x * blockDim.x;
  for (int i = blockIdx.x * blockDim.x + threadIdx.x; i * 4 < n; i += stride)
    reinterpret_cast<float4*>(p)[i] = make_float4(0.f, 0.f, 0.f, 0.f);
}

enum { M_BF16 = 0, M_SCORES, M_YACC, M_RELU, M_RES, M_F32B };

// C = A (M x K, row-major) * B^T (B stored N x K, row-major), bf16 in, fp32 accum.
// Batched over blockIdx.z with (z>>3, z&7) stride decomposition.
// rowBase: absolute row offset of A/C row 0 (for causal logic in M_SCORES / M_YACC).
template<int MODE>
__global__ __launch_bounds__(256)
void gemm_bt(const ushort* __restrict__ Abase, const ushort* __restrict__ Bbase,
             void* __restrict__ Cbase, int M, int N, int K,
             int lda, int ldb, int ldc, float scale,
             const float* __restrict__ bias, const ushort* __restrict__ resid,
             long sAhi, long sAlo, long sBhi, long sBlo, long sChi, long sClo,
             int rowBase)
{
  constexpr int BM = 64, BN = 64, BK = 32, LDP = 40;  // LDP: padded LDS row (bf16), 80B -> 2-way conflicts only
  const int z = blockIdx.z;
  const int zhi = z >> 3, zlo = z & 7;
  const ushort* A = Abase + (long)zhi * sAhi + (long)zlo * sAlo;
  const ushort* B = Bbase + (long)zhi * sBhi + (long)zlo * sBlo;

  const int m0 = blockIdx.y * BM, n0 = blockIdx.x * BN;
  if (MODE == M_SCORES && n0 > rowBase + m0 + (BM - 1)) return;  // fully-masked tile
  int kmax = K;
  if (MODE == M_YACC) kmax = min(K, rowBase + m0 + BM);          // causal K-limit (s <= t)

  __shared__ ushort As[BM * LDP], Bs[BN * LDP];

  const int tid = threadIdx.x;
  const int lane = tid & 63, wave = tid >> 6;
  const int wr = (wave >> 1) * 32, wc = (wave & 1) * 32;

  f32x4 acc[2][2] = {};

  const int srow = tid >> 2, skj = (tid & 3) * 8;
  const ushort* Ag = A + (long)(m0 + srow) * lda + skj;
  const ushort* Bg = B + (long)(n0 + srow) * ldb + skj;
  uint4* Asw = reinterpret_cast<uint4*>(&As[srow * LDP + skj]);
  uint4* Bsw = reinterpret_cast<uint4*>(&Bs[srow * LDP + skj]);

  const int fr = lane & 15, fg = lane >> 4;

  for (int k0 = 0; k0 < kmax; k0 += BK) {
    *Asw = *reinterpret_cast<const uint4*>(Ag + k0);
    *Bsw = *reinterpret_cast<const uint4*>(Bg + k0);
    __syncthreads();
    bf16x8 a0 = *reinterpret_cast<const bf16x8*>(&As[(wr +      fr) * LDP + fg * 8]);
    bf16x8 a1 = *reinterpret_cast<const bf16x8*>(&As[(wr + 16 + fr) * LDP + fg * 8]);
    bf16x8 b0 = *reinterpret_cast<const bf16x8*>(&Bs[(wc +      fr) * LDP + fg * 8]);
    bf16x8 b1 = *reinterpret_cast<const bf16x8*>(&Bs[(wc + 16 + fr) * LDP + fg * 8]);
    acc[0][0] = __builtin_amdgcn_mfma_f32_16x16x32_bf16(a0, b0, acc[0][0], 0, 0, 0);
    acc[0][1] = __builtin_amdgcn_mfma_f32_16x16x32_bf16(a0, b1, acc[0][1], 0, 0, 0);
    acc[1][0] = __builtin_amdgcn_mfma_f32_16x16x32_bf16(a1, b0, acc[1][0], 0, 0, 0);
    acc[1][1] = __builtin_amdgcn_mfma_f32_16x16x32_bf16(a1, b1, acc[1][1], 0, 0, 0);
    __syncthreads();
  }

  ushort* Cb = reinterpret_cast<ushort*>(Cbase);
  float*  Cf = reinterpret_cast<float*>(Cbase);
  const long coff = (long)zhi * sChi + (long)zlo * sClo;

#pragma unroll
  for (int mi = 0; mi < 2; ++mi)
#pragma unroll
    for (int ni = 0; ni < 2; ++ni) {
      int col = n0 + wc + ni * 16 + fr;
#pragma unroll
      for (int i = 0; i < 4; ++i) {
        int row = m0 + wr + mi * 16 + fg * 4 + i;   // verified C/D layout: col=lane&15, row=(lane>>4)*4+reg
        long idx = coff + (long)row * ldc + col;
        float v = acc[mi][ni][i];
        if (MODE == M_BF16)        { Cb[idx] = f2bf(v * scale); }
        else if (MODE == M_SCORES) { v *= scale; if (col > rowBase + row) v = 0.f; Cb[idx] = f2bf(v); }
        else if (MODE == M_YACC)   { atomicAdd(&Cf[idx], v); }
        else if (MODE == M_RELU)   { v += bias[col]; Cb[idx] = f2bf(fmaxf(v, 0.f)); }
        else if (MODE == M_RES)    { v += bias[col] + bf2f(resid[(long)row * ldc + col]); Cb[idx] = f2bf(v); }
        else                       { Cf[idx] = v + bias[col]; }
      }
    }
}

// LayerNorm(y + x) -> bf16; one block per row, D=512, 256 threads
__global__ __launch_bounds__(256)
void ln_k(const float* __restrict__ y, const float* __restrict__ x,
          const float* __restrict__ gamma, const float* __restrict__ beta,
          ushort* __restrict__ zb)
{
  const int r = blockIdx.x;
  const float* yr = y + (long)r * D_;
  const float* xr = x + (long)r * D_;
  int t = threadIdx.x;
  float v0 = yr[t] + xr[t];
  float v1 = yr[t + 256] + xr[t + 256];
  float s = v0 + v1, s2 = v0 * v0 + v1 * v1;
#pragma unroll
  for (int off = 1; off < 64; off <<= 1) {
    s  += __shfl_xor(s,  off);
    s2 += __shfl_xor(s2, off);
  }
  __shared__ float rs[4], rs2[4];
  int wave = t >> 6, lane = t & 63;
  if (lane == 0) { rs[wave] = s; rs2[wave] = s2; }
  __syncthreads();
  s  = rs[0] + rs[1] + rs[2] + rs[3];
  s2 = rs2[0] + rs2[1] + rs2[2] + rs2[3];
  float mean = s * (1.f / D_);
  float var  = s2 * (1.f / D_) - mean * mean;
  float rstd = rsqrtf(var + 1e-5f);
  zb[(long)r * D_ + t]       = f2bf((v0 - mean) * rstd * gamma[t] + beta[t]);
  zb[(long)r * D_ + t + 256] = f2bf((v1 - mean) * rstd * gamma[t + 256] + beta[t + 256]);
}

extern "C" void kernel_launch(void* const* d_in, const int* in_sizes, int n_in,
                              void* d_out, int out_size, void* d_ws, size_t ws_size,
                              hipStream_t stream)
{
  const float* x     = (const float*)d_in[0];
  const float* P     = (const float*)d_in[1];
  const float* Q     = (const float*)d_in[2];
  const float* gamma = (const float*)d_in[3];
  const float* beta  = (const float*)d_in[4];
  const float* W1    = (const float*)d_in[5];
  const float* b1    = (const float*)d_in[6];
  const float* W2    = (const float*)d_in[7];
  const float* b2    = (const float*)d_in[8];
  const float* Wp    = (const float*)d_in[9];
  const float* bp    = (const float*)d_in[10];
  float* out = (float*)d_out;

  char* ws = (char*)d_ws;
  size_t off = 0;
  auto alloc = [&](size_t bytes) -> char* {
    char* p = ws + off;
    off = (off + bytes + 255) & ~(size_t)255;
    return p;
  };
  const int BT = B_ * T_;  // 4096
  // Fixed allocations (~86.5 MB total):
  ushort* xb  = (ushort*)alloc((size_t)BT * D_ * 2);
  ushort* Qb  = (ushort*)alloc((size_t)H_ * D_ * D_ * 2);
  ushort* Pb  = (ushort*)alloc((size_t)H_ * D_ * D_ * 2);
  ushort* W1b = (ushort*)alloc((size_t)2 * D_ * D_ * 2);
  ushort* W2b = (ushort*)alloc((size_t)2 * D_ * D_ * 2);
  ushort* Wpb = (ushort*)alloc((size_t)D_ * D_ * 2);
  ushort* QZb = (ushort*)alloc((size_t)B_ * H_ * T_ * D_ * 2);  // 33.5 MB
  ushort* PZt = (ushort*)alloc((size_t)B_ * H_ * D_ * T_ * 2);  // transposed: [bh][e][s]
  float*  yb  = (float*)alloc((size_t)BT * D_ * 4);
  // Aliased into QZb (dead after the attention phase; stream order makes this safe):
  ushort* zb  = QZb;                                   // BT*D   (4 MB)
  ushort* m1b = QZb + (size_t)BT * D_;                 // BT*2D  (8 MB)
  ushort* z2b = QZb + (size_t)BT * D_ * 3;             // BT*D   (4 MB)  -- total 16/33.5 MB of QZb

  // Adaptive score-strip buffer: 16 group-buffers of stripRows x T bf16 each.
  size_t avail = ws_size > off ? ws_size - off : 0;
  int stripRows = 64;
  for (int r = T_; r >= 64; r >>= 1) {
    if ((size_t)16 * r * T_ * 2 <= avail) { stripRows = r; break; }
  }
  ushort* Sc = (ushort*)(ws + off);
  const long scStride = (long)stripRows * T_;  // elements per group-buffer

  // 1) converts + y zero
  cvt_bf16_k<<<512, 256, 0, stream>>>(x,  xb,  BT * D_);
  cvt_bf16_k<<<512, 256, 0, stream>>>(Q,  Qb,  H_ * D_ * D_);
  cvt_bf16_k<<<512, 256, 0, stream>>>(P,  Pb,  H_ * D_ * D_);
  cvt_bf16_k<<<256, 256, 0, stream>>>(W1, W1b, 2 * D_ * D_);
  cvt_bf16_k<<<256, 256, 0, stream>>>(W2, W2b, 2 * D_ * D_);
  cvt_bf16_k<<<128, 256, 0, stream>>>(Wp, Wpb, D_ * D_);
  zfill_k  <<<512, 256, 0, stream>>>(yb, BT * D_);

  const float rsd = 1.f / sqrtf((float)D_);

  // 2) QZ[bh] = x[b] @ Q[h]^T        (z = bh, 16-way batch)
  gemm_bt<M_BF16><<<dim3(D_ / 64, T_ / 64, 16), 256, 0, stream>>>(
      xb, Qb, QZb, T_, D_, D_, D_, D_, D_, 1.f, nullptr, nullptr,
      (long)T_ * D_, 0L, 0L, (long)D_ * D_, (long)8 * T_ * D_, (long)T_ * D_, 0);

  // 3) PZt[bh] = (P[h] @ x[b]^T) / H   -> [e][s], folds the 1/H
  gemm_bt<M_BF16><<<dim3(T_ / 64, D_ / 64, 16), 256, 0, stream>>>(
      Pb, xb, PZt, D_, T_, D_, D_, D_, T_, 1.f / H_, nullptr, nullptr,
      0L, (long)D_ * D_, (long)T_ * D_, 0L, (long)8 * D_ * T_, (long)D_ * T_, 0);

  // 4) per row-strip: scores (causal, scaled) then y += scores @ PZt^T, all 16 bh batched
  for (int s0r = 0; s0r < T_; s0r += stripRows) {
    gemm_bt<M_SCORES><<<dim3(T_ / 64, stripRows / 64, 16), 256, 0, stream>>>(
        QZb + (size_t)s0r * D_, xb, Sc,
        stripRows, T_, D_, D_, D_, T_, rsd, nullptr, nullptr,
        (long)8 * T_ * D_, (long)T_ * D_,
        (long)T_ * D_, 0L,
        8 * scStride, scStride,
        s0r);
    gemm_bt<M_YACC><<<dim3(D_ / 64, stripRows / 64, 16), 256, 0, stream>>>(
        Sc, PZt, yb + (size_t)s0r * D_,
        stripRows, D_, T_, T_, T_, D_, 1.f, nullptr, nullptr,
        8 * scStride, scStride,
        (long)8 * D_ * T_, (long)D_ * T_,
        (long)T_ * D_, 0L,
        s0r);
  }

  // 5) z = LN(y + x) -> bf16   (writes into aliased QZb region — QZb dead now)
  ln_k<<<BT, 256, 0, stream>>>(yb, x, gamma, beta, zb);

  // 6) MLP + residual + final projection
  gemm_bt<M_RELU><<<dim3(2 * D_ / 64, BT / 64, 1), 256, 0, stream>>>(
      zb, W1b, m1b, BT, 2 * D_, D_, D_, D_, 2 * D_, 1.f, b1, nullptr,
      0L, 0L, 0L, 0L, 0L, 0L, 0);
  gemm_bt<M_RES><<<dim3(D_ / 64, BT / 64, 1), 256, 0, stream>>>(
      m1b, W2b, z2b, BT, D_, 2 * D_, 2 * D_, 2 * D_, D_, 1.f, b2, zb,
      0L, 0L, 0L, 0L, 0L, 0L, 0);
  gemm_bt<M_F32B><<<dim3(D_ / 64, BT / 64, 1), 256, 0, stream>>>(
      z2b, Wpb, out, BT, D_, D_, D_, D_, D_, 1.f, bp, nullptr,
      0L, 0L, 0L, 0L, 0L, 0L, 0);
}

// Round 6
// 424.413 us; speedup vs baseline: 1.1155x; 1.1155x over previous
//
#include <hip/hip_runtime.h>
#include <hip/hip_bf16.h>
#include <cstdint>

#define DEV __device__ __forceinline__

typedef __attribute__((ext_vector_type(8))) short bf16x8;
typedef __attribute__((ext_vector_type(4))) float f32x4;

static constexpr int B_ = 2, T_ = 2048, D_ = 512, H_ = 8;

DEV ushort f2bf(float f) {
  union { float f; uint32_t u; } c; c.f = f;
  uint32_t u = c.u + 0x7fffu + ((c.u >> 16) & 1u);
  return (ushort)(u >> 16);
}
DEV float bf2f(ushort h) {
  union { uint32_t u; float f; } c; c.u = ((uint32_t)h) << 16; return c.f;
}

// async global->LDS, 16B per lane (m97 pattern; LDS dest = wave-uniform base + lane*16)
DEV void gload16(const ushort* g, ushort* l) {
  __builtin_amdgcn_global_load_lds(
      (const __attribute__((address_space(1))) void*)g,
      (__attribute__((address_space(3))) void*)l, 16, 0, 0);
}

// fp32 -> bf16 (n % 4 == 0)
__global__ void cvt_bf16_k(const float* __restrict__ in, ushort* __restrict__ out, int n) {
  int stride = gridDim.x * blockDim.x;
  for (int i = blockIdx.x * blockDim.x + threadIdx.x; i * 4 < n; i += stride) {
    float4 f = reinterpret_cast<const float4*>(in)[i];
    ushort4 o;
    o.x = f2bf(f.x); o.y = f2bf(f.y); o.z = f2bf(f.z); o.w = f2bf(f.w);
    reinterpret_cast<ushort4*>(out)[i] = o;
  }
}

__global__ void zfill_k(float* __restrict__ p, int n) {  // n % 4 == 0
  int stride = gridDim.x * blockDim.x;
  for (int i = blockIdx.x * blockDim.x + threadIdx.x; i * 4 < n; i += stride)
    reinterpret_cast<float4*>(p)[i] = make_float4(0.f, 0.f, 0.f, 0.f);
}

enum { M_BF16 = 0, M_SCORES, M_YACC, M_RELU, M_RES, M_F32B };

// C = A (M x K, rm) * B^T (B stored N x K, rm), bf16 in, fp32 accum.
// m97 structure: 128x128 tile, BK=32, 4 waves (64x64 each, 4x4 16x16 frags),
// linear LDS + global_load_lds width-16 staging.
// Batched over blockIdx.z: (z>>3, z&7) stride decomposition.
// rowBase: absolute row offset of A/C row 0 (causal logic in M_SCORES/M_YACC).
template<int MODE>
__global__ __launch_bounds__(256)
void gemm128(const ushort* __restrict__ Abase, const ushort* __restrict__ Bbase,
             void* __restrict__ Cbase, int K,
             int lda, int ldb, int ldc, float scale,
             const float* __restrict__ bias, const ushort* __restrict__ resid,
             long sAhi, long sAlo, long sBhi, long sBlo, long sChi, long sClo,
             int rowBase)
{
  constexpr int BM = 128, BN = 128, BK = 32;
  const int z = blockIdx.z;
  const int zhi = z >> 3, zlo = z & 7;
  const ushort* A = Abase + (long)zhi * sAhi + (long)zlo * sAlo;
  const ushort* B = Bbase + (long)zhi * sBhi + (long)zlo * sBlo;

  const int m0 = blockIdx.y * BM, n0 = blockIdx.x * BN;
  if (MODE == M_SCORES && n0 > rowBase + m0 + (BM - 1)) return;  // fully-masked tile
  int kmax = K;
  if (MODE == M_YACC) kmax = min(K, rowBase + m0 + BM);          // causal K-limit

  __shared__ ushort As[BM * BK], Bs[BN * BK];  // linear, 8KB each

  const int tid = threadIdx.x, lane = tid & 63, wave = tid >> 6;
  const int wr = (wave >> 1) * 64, wc = (wave & 1) * 64;
  const int fr = lane & 15, fg = lane >> 4;

  // staging: chunk c in {0,1}: row = tid/4 + c*64, k-octet = tid%4
  const int srow = tid >> 2, sk = (tid & 3) * 8;
  const ushort* Ag0 = A + (long)(m0 + srow) * lda + sk;
  const ushort* Ag1 = A + (long)(m0 + srow + 64) * lda + sk;
  const ushort* Bg0 = B + (long)(n0 + srow) * ldb + sk;
  const ushort* Bg1 = B + (long)(n0 + srow + 64) * ldb + sk;
  ushort* AsW0 = As + tid * 8;            // byte off = tid*16 (wave base + lane*16)
  ushort* AsW1 = As + tid * 8 + 2048;
  ushort* BsW0 = Bs + tid * 8;
  ushort* BsW1 = Bs + tid * 8 + 2048;

  f32x4 acc[4][4] = {};

  for (int k0 = 0; k0 < kmax; k0 += BK) {
    gload16(Ag0 + k0, AsW0);
    gload16(Ag1 + k0, AsW1);
    gload16(Bg0 + k0, BsW0);
    gload16(Bg1 + k0, BsW1);
    __syncthreads();  // compiler emits vmcnt(0) drain before barrier

    bf16x8 a[4], b[4];
#pragma unroll
    for (int mi = 0; mi < 4; ++mi)
      a[mi] = *reinterpret_cast<const bf16x8*>(&As[(wr + mi * 16 + fr) * BK + fg * 8]);
#pragma unroll
    for (int ni = 0; ni < 4; ++ni)
      b[ni] = *reinterpret_cast<const bf16x8*>(&Bs[(wc + ni * 16 + fr) * BK + fg * 8]);
#pragma unroll
    for (int mi = 0; mi < 4; ++mi)
#pragma unroll
      for (int ni = 0; ni < 4; ++ni)
        acc[mi][ni] = __builtin_amdgcn_mfma_f32_16x16x32_bf16(a[mi], b[ni], acc[mi][ni], 0, 0, 0);
    __syncthreads();
  }

  ushort* Cb = reinterpret_cast<ushort*>(Cbase);
  float*  Cf = reinterpret_cast<float*>(Cbase);
  const long coff = (long)zhi * sChi + (long)zlo * sClo;

#pragma unroll
  for (int mi = 0; mi < 4; ++mi)
#pragma unroll
    for (int ni = 0; ni < 4; ++ni) {
      int col = n0 + wc + ni * 16 + fr;
#pragma unroll
      for (int i = 0; i < 4; ++i) {
        int row = m0 + wr + mi * 16 + fg * 4 + i;   // C/D layout: col=lane&15, row=(lane>>4)*4+reg
        long idx = coff + (long)row * ldc + col;
        float v = acc[mi][ni][i];
        if (MODE == M_BF16)        { Cb[idx] = f2bf(v * scale); }
        else if (MODE == M_SCORES) { v *= scale; if (col > rowBase + row) v = 0.f; Cb[idx] = f2bf(v); }
        else if (MODE == M_YACC)   { atomicAdd(&Cf[idx], v); }
        else if (MODE == M_RELU)   { v += bias[col]; Cb[idx] = f2bf(fmaxf(v, 0.f)); }
        else if (MODE == M_RES)    { v += bias[col] + bf2f(resid[(long)row * ldc + col]); Cb[idx] = f2bf(v); }
        else                       { Cf[idx] = v + bias[col]; }
      }
    }
}

// LayerNorm(y + x) -> bf16; one block per row, D=512, 256 threads
__global__ __launch_bounds__(256)
void ln_k(const float* __restrict__ y, const float* __restrict__ x,
          const float* __restrict__ gamma, const float* __restrict__ beta,
          ushort* __restrict__ zb)
{
  const int r = blockIdx.x;
  const float* yr = y + (long)r * D_;
  const float* xr = x + (long)r * D_;
  int t = threadIdx.x;
  float v0 = yr[t] + xr[t];
  float v1 = yr[t + 256] + xr[t + 256];
  float s = v0 + v1, s2 = v0 * v0 + v1 * v1;
#pragma unroll
  for (int off = 1; off < 64; off <<= 1) {
    s  += __shfl_xor(s,  off);
    s2 += __shfl_xor(s2, off);
  }
  __shared__ float rs[4], rs2[4];
  int wave = t >> 6, lane = t & 63;
  if (lane == 0) { rs[wave] = s; rs2[wave] = s2; }
  __syncthreads();
  s  = rs[0] + rs[1] + rs[2] + rs[3];
  s2 = rs2[0] + rs2[1] + rs2[2] + rs2[3];
  float mean = s * (1.f / D_);
  float var  = s2 * (1.f / D_) - mean * mean;
  float rstd = rsqrtf(var + 1e-5f);
  zb[(long)r * D_ + t]       = f2bf((v0 - mean) * rstd * gamma[t] + beta[t]);
  zb[(long)r * D_ + t + 256] = f2bf((v1 - mean) * rstd * gamma[t + 256] + beta[t + 256]);
}

extern "C" void kernel_launch(void* const* d_in, const int* in_sizes, int n_in,
                              void* d_out, int out_size, void* d_ws, size_t ws_size,
                              hipStream_t stream)
{
  const float* x     = (const float*)d_in[0];
  const float* P     = (const float*)d_in[1];
  const float* Q     = (const float*)d_in[2];
  const float* gamma = (const float*)d_in[3];
  const float* beta  = (const float*)d_in[4];
  const float* W1    = (const float*)d_in[5];
  const float* b1    = (const float*)d_in[6];
  const float* W2    = (const float*)d_in[7];
  const float* b2    = (const float*)d_in[8];
  const float* Wp    = (const float*)d_in[9];
  const float* bp    = (const float*)d_in[10];
  float* out = (float*)d_out;

  char* ws = (char*)d_ws;
  size_t off = 0;
  auto alloc = [&](size_t bytes) -> char* {
    char* p = ws + off;
    off = (off + bytes + 255) & ~(size_t)255;
    return p;
  };
  const int BT = B_ * T_;  // 4096
  // Fixed allocations (~86.5 MB):
  ushort* xb  = (ushort*)alloc((size_t)BT * D_ * 2);
  ushort* Qb  = (ushort*)alloc((size_t)H_ * D_ * D_ * 2);
  ushort* Pb  = (ushort*)alloc((size_t)H_ * D_ * D_ * 2);
  ushort* W1b = (ushort*)alloc((size_t)2 * D_ * D_ * 2);
  ushort* W2b = (ushort*)alloc((size_t)2 * D_ * D_ * 2);
  ushort* Wpb = (ushort*)alloc((size_t)D_ * D_ * 2);
  ushort* QZb = (ushort*)alloc((size_t)B_ * H_ * T_ * D_ * 2);  // 33.5 MB
  ushort* PZt = (ushort*)alloc((size_t)B_ * H_ * D_ * T_ * 2);  // [bh][e][s]
  float*  yb  = (float*)alloc((size_t)BT * D_ * 4);
  // Aliased into QZb (dead after attention phase; stream order makes this safe):
  ushort* zb  = QZb;
  ushort* m1b = QZb + (size_t)BT * D_;
  ushort* z2b = QZb + (size_t)BT * D_ * 3;

  // Score buffer: nGrp group-buffers of stripRows x T bf16.
  size_t avail = ws_size > off ? ws_size - off : 0;
  int nGrp = 1, stripRows = 128;
  {
    const int cfgs[][2] = {{16,2048},{16,1024},{16,512},{16,256},{16,128},
                           {8,128},{4,128},{2,128},{1,128}};
    for (auto& c : cfgs) {
      if ((size_t)c[0] * c[1] * T_ * 2 <= avail) { nGrp = c[0]; stripRows = c[1]; break; }
    }
  }
  ushort* Sc = (ushort*)(ws + off);
  const long scStride = (long)stripRows * T_;

  // 1) converts + y zero
  cvt_bf16_k<<<512, 256, 0, stream>>>(x,  xb,  BT * D_);
  cvt_bf16_k<<<512, 256, 0, stream>>>(Q,  Qb,  H_ * D_ * D_);
  cvt_bf16_k<<<512, 256, 0, stream>>>(P,  Pb,  H_ * D_ * D_);
  cvt_bf16_k<<<256, 256, 0, stream>>>(W1, W1b, 2 * D_ * D_);
  cvt_bf16_k<<<256, 256, 0, stream>>>(W2, W2b, 2 * D_ * D_);
  cvt_bf16_k<<<128, 256, 0, stream>>>(Wp, Wpb, D_ * D_);
  zfill_k  <<<512, 256, 0, stream>>>(yb, BT * D_);

  const float rsd = 1.f / sqrtf((float)D_);

  // 2) QZ[bh] = x[b] @ Q[h]^T   (z = bh, 16-way)
  gemm128<M_BF16><<<dim3(D_ / 128, T_ / 128, 16), 256, 0, stream>>>(
      xb, Qb, QZb, D_, D_, D_, D_, 1.f, nullptr, nullptr,
      (long)T_ * D_, 0L, 0L, (long)D_ * D_, (long)8 * T_ * D_, (long)T_ * D_, 0);

  // 3) PZt[bh] = (P[h] @ x[b]^T) / H   -> [e][s]
  gemm128<M_BF16><<<dim3(T_ / 128, D_ / 128, 16), 256, 0, stream>>>(
      Pb, xb, PZt, D_, D_, D_, T_, 1.f / H_, nullptr, nullptr,
      0L, (long)D_ * D_, (long)T_ * D_, 0L, (long)8 * D_ * T_, (long)D_ * T_, 0);

  // 4) per group-chunk, per row-strip: scores (causal) then y += scores @ PZt^T
  for (int g0 = 0; g0 < 16; g0 += nGrp) {
    const int b0 = g0 >> 3;
    const long sBhiS = (nGrp == 16) ? (long)T_ * D_ : 0L;       // xb batch stride
    const long sChiY = (nGrp == 16) ? (long)T_ * D_ : 0L;       // yb batch stride
    const long sAhiS = (long)8 * T_ * D_;                        // QZ hi stride (z>=8 only when nGrp=16)
    const long sBhiY = (long)8 * D_ * T_;                        // PZt hi stride
    for (int s0r = 0; s0r < T_; s0r += stripRows) {
      gemm128<M_SCORES><<<dim3(T_ / 128, stripRows / 128, nGrp), 256, 0, stream>>>(
          QZb + (size_t)g0 * T_ * D_ + (size_t)s0r * D_,
          xb + (size_t)b0 * T_ * D_, Sc,
          D_, D_, D_, T_, rsd, nullptr, nullptr,
          sAhiS, (long)T_ * D_,
          sBhiS, 0L,
          8 * scStride, scStride,
          s0r);
      gemm128<M_YACC><<<dim3(D_ / 128, stripRows / 128, nGrp), 256, 0, stream>>>(
          Sc, PZt + (size_t)g0 * D_ * T_,
          yb + (size_t)b0 * T_ * D_ + (size_t)s0r * D_,
          T_, T_, T_, D_, 1.f, nullptr, nullptr,
          8 * scStride, scStride,
          sBhiY, (long)D_ * T_,
          sChiY, 0L,
          s0r);
    }
  }

  // 5) z = LN(y + x) -> bf16   (into aliased QZb region)
  ln_k<<<BT, 256, 0, stream>>>(yb, x, gamma, beta, zb);

  // 6) MLP + residual + final projection
  gemm128<M_RELU><<<dim3(2 * D_ / 128, BT / 128, 1), 256, 0, stream>>>(
      zb, W1b, m1b, D_, D_, D_, 2 * D_, 1.f, b1, nullptr,
      0L, 0L, 0L, 0L, 0L, 0L, 0);
  gemm128<M_RES><<<dim3(D_ / 128, BT / 128, 1), 256, 0, stream>>>(
      m1b, W2b, z2b, 2 * D_, 2 * D_, 2 * D_, D_, 1.f, b2, zb,
      0L, 0L, 0L, 0L, 0L, 0L, 0);
  gemm128<M_F32B><<<dim3(D_ / 128, BT / 128, 1), 256, 0, stream>>>(
      z2b, Wpb, out, D_, D_, D_, D_, 1.f, bp, nullptr,
      0L, 0L, 0L, 0L, 0L, 0L, 0);
}

// Round 7
// 403.554 us; speedup vs baseline: 1.1731x; 1.0517x over previous
//
#include <hip/hip_runtime.h>
#include <hip/hip_bf16.h>
#include <cstdint>

#define DEV __device__ __forceinline__

typedef __attribute__((ext_vector_type(8))) short bf16x8;
typedef __attribute__((ext_vector_type(4))) float f32x4;

static constexpr int B_ = 2, T_ = 2048, D_ = 512, H_ = 8;

DEV ushort f2bf(float f) {
  union { float f; uint32_t u; } c; c.f = f;
  uint32_t u = c.u + 0x7fffu + ((c.u >> 16) & 1u);
  return (ushort)(u >> 16);
}
DEV float bf2f(ushort h) {
  union { uint32_t u; float f; } c; c.u = ((uint32_t)h) << 16; return c.f;
}

// async global->LDS, 16B per lane (m97 pattern; LDS dest = wave-uniform base + lane*16)
DEV void gload16(const ushort* g, ushort* l) {
  __builtin_amdgcn_global_load_lds(
      (const __attribute__((address_space(1))) void*)g,
      (__attribute__((address_space(3))) void*)l, 16, 0, 0);
}

// fp32 -> bf16 (n % 4 == 0)
__global__ void cvt_bf16_k(const float* __restrict__ in, ushort* __restrict__ out, int n) {
  int stride = gridDim.x * blockDim.x;
  for (int i = blockIdx.x * blockDim.x + threadIdx.x; i * 4 < n; i += stride) {
    float4 f = reinterpret_cast<const float4*>(in)[i];
    ushort4 o;
    o.x = f2bf(f.x); o.y = f2bf(f.y); o.z = f2bf(f.z); o.w = f2bf(f.w);
    reinterpret_cast<ushort4*>(out)[i] = o;
  }
}

__global__ void zfill_k(float* __restrict__ p, int n) {  // n % 4 == 0
  int stride = gridDim.x * blockDim.x;
  for (int i = blockIdx.x * blockDim.x + threadIdx.x; i * 4 < n; i += stride)
    reinterpret_cast<float4*>(p)[i] = make_float4(0.f, 0.f, 0.f, 0.f);
}

enum { M_BF16 = 0, M_SCORES, M_YACC, M_RELU, M_RES, M_F32B };

// C = A (M x K, rm) * B^T (B stored N x K, rm), bf16 in, fp32 accum.
// 128x128 tile, BK=32, 4 waves (64x64 each, 4x4 16x16 frags),
// linear LDS + global_load_lds width-16 staging,
// 2-phase double-buffer prefetch (T3-minimum): STAGE(t+1) issued BEFORE
// ds_read+MFMA of tile t, so the vmcnt(0) drain at the barrier overlaps
// the load latency with compute instead of exposing it serially.
// Batched over blockIdx.z: (z>>3, z&7) stride decomposition.
// rowBase: absolute row offset of A/C row 0 (causal logic in M_SCORES/M_YACC).
template<int MODE>
__global__ __launch_bounds__(256)
void gemm128(const ushort* __restrict__ Abase, const ushort* __restrict__ Bbase,
             void* __restrict__ Cbase, int K,
             int lda, int ldb, int ldc, float scale,
             const float* __restrict__ bias, const ushort* __restrict__ resid,
             long sAhi, long sAlo, long sBhi, long sBlo, long sChi, long sClo,
             int rowBase)
{
  constexpr int BM = 128, BN = 128, BK = 32;
  const int z = blockIdx.z;
  const int zhi = z >> 3, zlo = z & 7;
  const ushort* A = Abase + (long)zhi * sAhi + (long)zlo * sAlo;
  const ushort* B = Bbase + (long)zhi * sBhi + (long)zlo * sBlo;

  const int m0 = blockIdx.y * BM, n0 = blockIdx.x * BN;
  if (MODE == M_SCORES && n0 > rowBase + m0 + (BM - 1)) return;  // fully-masked tile
  int kmax = K;
  if (MODE == M_YACC) kmax = min(K, rowBase + m0 + BM);          // causal K-limit

  __shared__ ushort As[2][BM * BK], Bs[2][BN * BK];  // double-buffered, 2x(8KB+8KB)

  const int tid = threadIdx.x, lane = tid & 63, wave = tid >> 6;
  const int wr = (wave >> 1) * 64, wc = (wave & 1) * 64;
  const int fr = lane & 15, fg = lane >> 4;

  // staging: chunk c in {0,1}: row = tid/4 + c*64, k-octet = tid%4
  const int srow = tid >> 2, sk = (tid & 3) * 8;
  const ushort* Ag0 = A + (long)(m0 + srow) * lda + sk;
  const ushort* Ag1 = A + (long)(m0 + srow + 64) * lda + sk;
  const ushort* Bg0 = B + (long)(n0 + srow) * ldb + sk;
  const ushort* Bg1 = B + (long)(n0 + srow + 64) * ldb + sk;
  const int soff = tid * 8;  // LDS dest byte off = tid*16 (wave base + lane*16)

  f32x4 acc[4][4] = {};

  const int nt = kmax / BK;  // kmax is always a multiple of BK here
  // prologue: stage tile 0
  gload16(Ag0, As[0] + soff);
  gload16(Ag1, As[0] + soff + 2048);
  gload16(Bg0, Bs[0] + soff);
  gload16(Bg1, Bs[0] + soff + 2048);
  __syncthreads();

  int cur = 0;
  for (int t = 0; t < nt; ++t) {
    // issue next-tile prefetch FIRST (stays in flight across ds_read+MFMA)
    if (t + 1 < nt) {
      const int kn = (t + 1) * BK;
      const int nb = cur ^ 1;
      gload16(Ag0 + kn, As[nb] + soff);
      gload16(Ag1 + kn, As[nb] + soff + 2048);
      gload16(Bg0 + kn, Bs[nb] + soff);
      gload16(Bg1 + kn, Bs[nb] + soff + 2048);
    }
    const ushort* Asc = As[cur];
    const ushort* Bsc = Bs[cur];
    bf16x8 a[4], b[4];
#pragma unroll
    for (int mi = 0; mi < 4; ++mi)
      a[mi] = *reinterpret_cast<const bf16x8*>(&Asc[(wr + mi * 16 + fr) * BK + fg * 8]);
#pragma unroll
    for (int ni = 0; ni < 4; ++ni)
      b[ni] = *reinterpret_cast<const bf16x8*>(&Bsc[(wc + ni * 16 + fr) * BK + fg * 8]);
#pragma unroll
    for (int mi = 0; mi < 4; ++mi)
#pragma unroll
      for (int ni = 0; ni < 4; ++ni)
        acc[mi][ni] = __builtin_amdgcn_mfma_f32_16x16x32_bf16(a[mi], b[ni], acc[mi][ni], 0, 0, 0);
    __syncthreads();  // drains the in-flight prefetch (vmcnt(0)) AFTER compute
    cur ^= 1;
  }

  ushort* Cb = reinterpret_cast<ushort*>(Cbase);
  float*  Cf = reinterpret_cast<float*>(Cbase);
  const long coff = (long)zhi * sChi + (long)zlo * sClo;

#pragma unroll
  for (int mi = 0; mi < 4; ++mi)
#pragma unroll
    for (int ni = 0; ni < 4; ++ni) {
      int col = n0 + wc + ni * 16 + fr;
#pragma unroll
      for (int i = 0; i < 4; ++i) {
        int row = m0 + wr + mi * 16 + fg * 4 + i;   // C/D layout: col=lane&15, row=(lane>>4)*4+reg
        long idx = coff + (long)row * ldc + col;
        float v = acc[mi][ni][i];
        if (MODE == M_BF16)        { Cb[idx] = f2bf(v * scale); }
        else if (MODE == M_SCORES) { v *= scale; if (col > rowBase + row) v = 0.f; Cb[idx] = f2bf(v); }
        else if (MODE == M_YACC)   { atomicAdd(&Cf[idx], v); }
        else if (MODE == M_RELU)   { v += bias[col]; Cb[idx] = f2bf(fmaxf(v, 0.f)); }
        else if (MODE == M_RES)    { v += bias[col] + bf2f(resid[(long)row * ldc + col]); Cb[idx] = f2bf(v); }
        else                       { Cf[idx] = v + bias[col]; }
      }
    }
}

// LayerNorm(y + x) -> bf16; one block per row, D=512, 256 threads
__global__ __launch_bounds__(256)
void ln_k(const float* __restrict__ y, const float* __restrict__ x,
          const float* __restrict__ gamma, const float* __restrict__ beta,
          ushort* __restrict__ zb)
{
  const int r = blockIdx.x;
  const float* yr = y + (long)r * D_;
  const float* xr = x + (long)r * D_;
  int t = threadIdx.x;
  float v0 = yr[t] + xr[t];
  float v1 = yr[t + 256] + xr[t + 256];
  float s = v0 + v1, s2 = v0 * v0 + v1 * v1;
#pragma unroll
  for (int off = 1; off < 64; off <<= 1) {
    s  += __shfl_xor(s,  off);
    s2 += __shfl_xor(s2, off);
  }
  __shared__ float rs[4], rs2[4];
  int wave = t >> 6, lane = t & 63;
  if (lane == 0) { rs[wave] = s; rs2[wave] = s2; }
  __syncthreads();
  s  = rs[0] + rs[1] + rs[2] + rs[3];
  s2 = rs2[0] + rs2[1] + rs2[2] + rs2[3];
  float mean = s * (1.f / D_);
  float var  = s2 * (1.f / D_) - mean * mean;
  float rstd = rsqrtf(var + 1e-5f);
  zb[(long)r * D_ + t]       = f2bf((v0 - mean) * rstd * gamma[t] + beta[t]);
  zb[(long)r * D_ + t + 256] = f2bf((v1 - mean) * rstd * gamma[t + 256] + beta[t + 256]);
}

extern "C" void kernel_launch(void* const* d_in, const int* in_sizes, int n_in,
                              void* d_out, int out_size, void* d_ws, size_t ws_size,
                              hipStream_t stream)
{
  const float* x     = (const float*)d_in[0];
  const float* P     = (const float*)d_in[1];
  const float* Q     = (const float*)d_in[2];
  const float* gamma = (const float*)d_in[3];
  const float* beta  = (const float*)d_in[4];
  const float* W1    = (const float*)d_in[5];
  const float* b1    = (const float*)d_in[6];
  const float* W2    = (const float*)d_in[7];
  const float* b2    = (const float*)d_in[8];
  const float* Wp    = (const float*)d_in[9];
  const float* bp    = (const float*)d_in[10];
  float* out = (float*)d_out;

  char* ws = (char*)d_ws;
  size_t off = 0;
  auto alloc = [&](size_t bytes) -> char* {
    char* p = ws + off;
    off = (off + bytes + 255) & ~(size_t)255;
    return p;
  };
  const int BT = B_ * T_;  // 4096
  // Fixed allocations (~86.5 MB):
  ushort* xb  = (ushort*)alloc((size_t)BT * D_ * 2);
  ushort* Qb  = (ushort*)alloc((size_t)H_ * D_ * D_ * 2);
  ushort* Pb  = (ushort*)alloc((size_t)H_ * D_ * D_ * 2);
  ushort* W1b = (ushort*)alloc((size_t)2 * D_ * D_ * 2);
  ushort* W2b = (ushort*)alloc((size_t)2 * D_ * D_ * 2);
  ushort* Wpb = (ushort*)alloc((size_t)D_ * D_ * 2);
  ushort* QZb = (ushort*)alloc((size_t)B_ * H_ * T_ * D_ * 2);  // 33.5 MB
  ushort* PZt = (ushort*)alloc((size_t)B_ * H_ * D_ * T_ * 2);  // [bh][e][s]
  float*  yb  = (float*)alloc((size_t)BT * D_ * 4);
  // Aliased into QZb (dead after attention phase; stream order makes this safe):
  ushort* zb  = QZb;
  ushort* m1b = QZb + (size_t)BT * D_;
  ushort* z2b = QZb + (size_t)BT * D_ * 3;

  // Score buffer: nGrp group-buffers of stripRows x T bf16.
  size_t avail = ws_size > off ? ws_size - off : 0;
  int nGrp = 1, stripRows = 128;
  {
    const int cfgs[][2] = {{16,2048},{16,1024},{16,512},{16,256},{16,128},
                           {8,128},{4,128},{2,128},{1,128}};
    for (auto& c : cfgs) {
      if ((size_t)c[0] * c[1] * T_ * 2 <= avail) { nGrp = c[0]; stripRows = c[1]; break; }
    }
  }
  ushort* Sc = (ushort*)(ws + off);
  const long scStride = (long)stripRows * T_;

  // 1) converts + y zero
  cvt_bf16_k<<<512, 256, 0, stream>>>(x,  xb,  BT * D_);
  cvt_bf16_k<<<512, 256, 0, stream>>>(Q,  Qb,  H_ * D_ * D_);
  cvt_bf16_k<<<512, 256, 0, stream>>>(P,  Pb,  H_ * D_ * D_);
  cvt_bf16_k<<<256, 256, 0, stream>>>(W1, W1b, 2 * D_ * D_);
  cvt_bf16_k<<<256, 256, 0, stream>>>(W2, W2b, 2 * D_ * D_);
  cvt_bf16_k<<<128, 256, 0, stream>>>(Wp, Wpb, D_ * D_);
  zfill_k  <<<512, 256, 0, stream>>>(yb, BT * D_);

  const float rsd = 1.f / sqrtf((float)D_);

  // 2) QZ[bh] = x[b] @ Q[h]^T   (z = bh, 16-way)
  gemm128<M_BF16><<<dim3(D_ / 128, T_ / 128, 16), 256, 0, stream>>>(
      xb, Qb, QZb, D_, D_, D_, D_, 1.f, nullptr, nullptr,
      (long)T_ * D_, 0L, 0L, (long)D_ * D_, (long)8 * T_ * D_, (long)T_ * D_, 0);

  // 3) PZt[bh] = (P[h] @ x[b]^T) / H   -> [e][s]
  gemm128<M_BF16><<<dim3(T_ / 128, D_ / 128, 16), 256, 0, stream>>>(
      Pb, xb, PZt, D_, D_, D_, T_, 1.f / H_, nullptr, nullptr,
      0L, (long)D_ * D_, (long)T_ * D_, 0L, (long)8 * D_ * T_, (long)D_ * T_, 0);

  // 4) per group-chunk, per row-strip: scores (causal) then y += scores @ PZt^T
  for (int g0 = 0; g0 < 16; g0 += nGrp) {
    const int b0 = g0 >> 3;
    const long sBhiS = (nGrp == 16) ? (long)T_ * D_ : 0L;       // xb batch stride
    const long sChiY = (nGrp == 16) ? (long)T_ * D_ : 0L;       // yb batch stride
    const long sAhiS = (long)8 * T_ * D_;                        // QZ hi stride (z>=8 only when nGrp=16)
    const long sBhiY = (long)8 * D_ * T_;                        // PZt hi stride
    for (int s0r = 0; s0r < T_; s0r += stripRows) {
      gemm128<M_SCORES><<<dim3(T_ / 128, stripRows / 128, nGrp), 256, 0, stream>>>(
          QZb + (size_t)g0 * T_ * D_ + (size_t)s0r * D_,
          xb + (size_t)b0 * T_ * D_, Sc,
          D_, D_, D_, T_, rsd, nullptr, nullptr,
          sAhiS, (long)T_ * D_,
          sBhiS, 0L,
          8 * scStride, scStride,
          s0r);
      gemm128<M_YACC><<<dim3(D_ / 128, stripRows / 128, nGrp), 256, 0, stream>>>(
          Sc, PZt + (size_t)g0 * D_ * T_,
          yb + (size_t)b0 * T_ * D_ + (size_t)s0r * D_,
          T_, T_, T_, D_, 1.f, nullptr, nullptr,
          8 * scStride, scStride,
          sBhiY, (long)D_ * T_,
          sChiY, 0L,
          s0r);
    }
  }

  // 5) z = LN(y + x) -> bf16   (into aliased QZb region)
  ln_k<<<BT, 256, 0, stream>>>(yb, x, gamma, beta, zb);

  // 6) MLP + residual + final projection
  gemm128<M_RELU><<<dim3(2 * D_ / 128, BT / 128, 1), 256, 0, stream>>>(
      zb, W1b, m1b, D_, D_, D_, 2 * D_, 1.f, b1, nullptr,
      0L, 0L, 0L, 0L, 0L, 0L, 0);
  gemm128<M_RES><<<dim3(D_ / 128, BT / 128, 1), 256, 0, stream>>>(
      m1b, W2b, z2b, 2 * D_, 2 * D_, 2 * D_, D_, 1.f, b2, zb,
      0L, 0L, 0L, 0L, 0L, 0L, 0);
  gemm128<M_F32B><<<dim3(D_ / 128, BT / 128, 1), 256, 0, stream>>>(
      z2b, Wpb, out, D_, D_, D_, D_, 1.f, bp, nullptr,
      0L, 0L, 0L, 0L, 0L, 0L, 0);
}

// Round 8
// 382.896 us; speedup vs baseline: 1.2364x; 1.0540x over previous
//
#include <hip/hip_runtime.h>
#include <hip/hip_bf16.h>
#include <cstdint>

#define DEV __device__ __forceinline__

typedef __attribute__((ext_vector_type(8))) short bf16x8;
typedef __attribute__((ext_vector_type(4))) float f32x4;

static constexpr int B_ = 2, T_ = 2048, D_ = 512, H_ = 8;

DEV ushort f2bf(float f) {
  union { float f; uint32_t u; } c; c.f = f;
  uint32_t u = c.u + 0x7fffu + ((c.u >> 16) & 1u);
  return (ushort)(u >> 16);
}
DEV float bf2f(ushort h) {
  union { uint32_t u; float f; } c; c.u = ((uint32_t)h) << 16; return c.f;
}

// async global->LDS, 16B per lane (LDS dest = wave-uniform base + lane*16)
DEV void gload16(const ushort* g, ushort* l) {
  __builtin_amdgcn_global_load_lds(
      (const __attribute__((address_space(1))) void*)g,
      (__attribute__((address_space(3))) void*)l, 16, 0, 0);
}

// fp32 -> bf16 (n % 4 == 0)
__global__ void cvt_bf16_k(const float* __restrict__ in, ushort* __restrict__ out, int n) {
  int stride = gridDim.x * blockDim.x;
  for (int i = blockIdx.x * blockDim.x + threadIdx.x; i * 4 < n; i += stride) {
    float4 f = reinterpret_cast<const float4*>(in)[i];
    ushort4 o;
    o.x = f2bf(f.x); o.y = f2bf(f.y); o.z = f2bf(f.z); o.w = f2bf(f.w);
    reinterpret_cast<ushort4*>(out)[i] = o;
  }
}

__global__ void zfill_k(float* __restrict__ p, int n) {  // n % 4 == 0
  int stride = gridDim.x * blockDim.x;
  for (int i = blockIdx.x * blockDim.x + threadIdx.x; i * 4 < n; i += stride)
    reinterpret_cast<float4*>(p)[i] = make_float4(0.f, 0.f, 0.f, 0.f);
}

enum { M_BF16 = 0, M_SCORES, M_YACC, M_RELU, M_RES, M_F32B };

// C = A (M x K, rm) * B^T (B stored N x K, rm), bf16 in, fp32 accum.
// 128x128 tile, BK=32, *8 waves* (wave tile 64x32: 4 m-frags x 2 n-frags),
// linear LDS + global_load_lds width-16, 2-phase double-buffer prefetch.
// Register budget: acc 8*f32x4 = 32 acc-regs + ~60 arch => <=128 total
// => 4 waves/SIMD occupancy bucket (vs 2 for the 4-wave 64x64 variant).
// Batched over blockIdx.z: (z>>3, z&7) stride decomposition.
// rowBase: absolute row offset of A/C row 0 (causal logic in M_SCORES/M_YACC).
template<int MODE>
__global__ __launch_bounds__(512)
void gemm128(const ushort* __restrict__ Abase, const ushort* __restrict__ Bbase,
             void* __restrict__ Cbase, int K,
             int lda, int ldb, int ldc, float scale,
             const float* __restrict__ bias, const ushort* __restrict__ resid,
             long sAhi, long sAlo, long sBhi, long sBlo, long sChi, long sClo,
             int rowBase)
{
  constexpr int BM = 128, BN = 128, BK = 32;
  const int z = blockIdx.z;
  const int zhi = z >> 3, zlo = z & 7;
  const ushort* A = Abase + (long)zhi * sAhi + (long)zlo * sAlo;
  const ushort* B = Bbase + (long)zhi * sBhi + (long)zlo * sBlo;

  const int m0 = blockIdx.y * BM, n0 = blockIdx.x * BN;
  if (MODE == M_SCORES && n0 > rowBase + m0 + (BM - 1)) return;  // fully-masked tile
  int kmax = K;
  if (MODE == M_YACC) kmax = min(K, rowBase + m0 + BM);          // causal K-limit

  __shared__ ushort As[2][BM * BK], Bs[2][BN * BK];  // double-buffered, 32KB total

  const int tid = threadIdx.x, lane = tid & 63, wave = tid >> 6;  // 8 waves
  const int wr = (wave >> 2) * 64, wc = (wave & 3) * 32;          // 2M x 4N wave grid
  const int fr = lane & 15, fg = lane >> 4;

  // staging: 512 threads cover one 128x32 tile per array: row = tid/4, k-octet = tid%4
  const int srow = tid >> 2, sk = (tid & 3) * 8;
  const ushort* Ag = A + (long)(m0 + srow) * lda + sk;
  const ushort* Bg = B + (long)(n0 + srow) * ldb + sk;
  const int soff = tid * 8;  // LDS elem off; byte off = tid*16 = wave*1024 + lane*16

  f32x4 acc[4][2] = {};

  const int nt = kmax / BK;  // kmax is always a multiple of BK here
  // prologue: stage tile 0
  gload16(Ag, As[0] + soff);
  gload16(Bg, Bs[0] + soff);
  __syncthreads();

  int cur = 0;
  for (int t = 0; t < nt; ++t) {
    // issue next-tile prefetch FIRST (stays in flight across ds_read+MFMA)
    if (t + 1 < nt) {
      const int kn = (t + 1) * BK;
      const int nb = cur ^ 1;
      gload16(Ag + kn, As[nb] + soff);
      gload16(Bg + kn, Bs[nb] + soff);
    }
    const ushort* Asc = As[cur];
    const ushort* Bsc = Bs[cur];
    bf16x8 a[4], b[2];
#pragma unroll
    for (int mi = 0; mi < 4; ++mi)
      a[mi] = *reinterpret_cast<const bf16x8*>(&Asc[(wr + mi * 16 + fr) * BK + fg * 8]);
#pragma unroll
    for (int ni = 0; ni < 2; ++ni)
      b[ni] = *reinterpret_cast<const bf16x8*>(&Bsc[(wc + ni * 16 + fr) * BK + fg * 8]);
#pragma unroll
    for (int mi = 0; mi < 4; ++mi)
#pragma unroll
      for (int ni = 0; ni < 2; ++ni)
        acc[mi][ni] = __builtin_amdgcn_mfma_f32_16x16x32_bf16(a[mi], b[ni], acc[mi][ni], 0, 0, 0);
    __syncthreads();  // drains the in-flight prefetch (vmcnt(0)) AFTER compute
    cur ^= 1;
  }

  ushort* Cb = reinterpret_cast<ushort*>(Cbase);
  float*  Cf = reinterpret_cast<float*>(Cbase);
  const long coff = (long)zhi * sChi + (long)zlo * sClo;

#pragma unroll
  for (int mi = 0; mi < 4; ++mi)
#pragma unroll
    for (int ni = 0; ni < 2; ++ni) {
      int col = n0 + wc + ni * 16 + fr;
#pragma unroll
      for (int i = 0; i < 4; ++i) {
        int row = m0 + wr + mi * 16 + fg * 4 + i;   // C/D layout: col=lane&15, row=(lane>>4)*4+reg
        long idx = coff + (long)row * ldc + col;
        float v = acc[mi][ni][i];
        if (MODE == M_BF16)        { Cb[idx] = f2bf(v * scale); }
        else if (MODE == M_SCORES) { v *= scale; if (col > rowBase + row) v = 0.f; Cb[idx] = f2bf(v); }
        else if (MODE == M_YACC)   { atomicAdd(&Cf[idx], v); }
        else if (MODE == M_RELU)   { v += bias[col]; Cb[idx] = f2bf(fmaxf(v, 0.f)); }
        else if (MODE == M_RES)    { v += bias[col] + bf2f(resid[(long)row * ldc + col]); Cb[idx] = f2bf(v); }
        else                       { Cf[idx] = v + bias[col]; }
      }
    }
}

// LayerNorm(y + x) -> bf16; one block per row, D=512, 256 threads
__global__ __launch_bounds__(256)
void ln_k(const float* __restrict__ y, const float* __restrict__ x,
          const float* __restrict__ gamma, const float* __restrict__ beta,
          ushort* __restrict__ zb)
{
  const int r = blockIdx.x;
  const float* yr = y + (long)r * D_;
  const float* xr = x + (long)r * D_;
  int t = threadIdx.x;
  float v0 = yr[t] + xr[t];
  float v1 = yr[t + 256] + xr[t + 256];
  float s = v0 + v1, s2 = v0 * v0 + v1 * v1;
#pragma unroll
  for (int off = 1; off < 64; off <<= 1) {
    s  += __shfl_xor(s,  off);
    s2 += __shfl_xor(s2, off);
  }
  __shared__ float rs[4], rs2[4];
  int wave = t >> 6, lane = t & 63;
  if (lane == 0) { rs[wave] = s; rs2[wave] = s2; }
  __syncthreads();
  s  = rs[0] + rs[1] + rs[2] + rs[3];
  s2 = rs2[0] + rs2[1] + rs2[2] + rs2[3];
  float mean = s * (1.f / D_);
  float var  = s2 * (1.f / D_) - mean * mean;
  float rstd = rsqrtf(var + 1e-5f);
  zb[(long)r * D_ + t]       = f2bf((v0 - mean) * rstd * gamma[t] + beta[t]);
  zb[(long)r * D_ + t + 256] = f2bf((v1 - mean) * rstd * gamma[t + 256] + beta[t + 256]);
}

extern "C" void kernel_launch(void* const* d_in, const int* in_sizes, int n_in,
                              void* d_out, int out_size, void* d_ws, size_t ws_size,
                              hipStream_t stream)
{
  const float* x     = (const float*)d_in[0];
  const float* P     = (const float*)d_in[1];
  const float* Q     = (const float*)d_in[2];
  const float* gamma = (const float*)d_in[3];
  const float* beta  = (const float*)d_in[4];
  const float* W1    = (const float*)d_in[5];
  const float* b1    = (const float*)d_in[6];
  const float* W2    = (const float*)d_in[7];
  const float* b2    = (const float*)d_in[8];
  const float* Wp    = (const float*)d_in[9];
  const float* bp    = (const float*)d_in[10];
  float* out = (float*)d_out;

  char* ws = (char*)d_ws;
  size_t off = 0;
  auto alloc = [&](size_t bytes) -> char* {
    char* p = ws + off;
    off = (off + bytes + 255) & ~(size_t)255;
    return p;
  };
  const int BT = B_ * T_;  // 4096
  // Fixed allocations (~86.5 MB):
  ushort* xb  = (ushort*)alloc((size_t)BT * D_ * 2);
  ushort* Qb  = (ushort*)alloc((size_t)H_ * D_ * D_ * 2);
  ushort* Pb  = (ushort*)alloc((size_t)H_ * D_ * D_ * 2);
  ushort* W1b = (ushort*)alloc((size_t)2 * D_ * D_ * 2);
  ushort* W2b = (ushort*)alloc((size_t)2 * D_ * D_ * 2);
  ushort* Wpb = (ushort*)alloc((size_t)D_ * D_ * 2);
  ushort* QZb = (ushort*)alloc((size_t)B_ * H_ * T_ * D_ * 2);  // 33.5 MB
  ushort* PZt = (ushort*)alloc((size_t)B_ * H_ * D_ * T_ * 2);  // [bh][e][s]
  float*  yb  = (float*)alloc((size_t)BT * D_ * 4);
  // Aliased into QZb (dead after attention phase; stream order makes this safe):
  ushort* zb  = QZb;
  ushort* m1b = QZb + (size_t)BT * D_;
  ushort* z2b = QZb + (size_t)BT * D_ * 3;

  // Score buffer: nGrp group-buffers of stripRows x T bf16.
  size_t avail = ws_size > off ? ws_size - off : 0;
  int nGrp = 1, stripRows = 128;
  {
    const int cfgs[][2] = {{16,2048},{16,1024},{16,512},{16,256},{16,128},
                           {8,128},{4,128},{2,128},{1,128}};
    for (auto& c : cfgs) {
      if ((size_t)c[0] * c[1] * T_ * 2 <= avail) { nGrp = c[0]; stripRows = c[1]; break; }
    }
  }
  ushort* Sc = (ushort*)(ws + off);
  const long scStride = (long)stripRows * T_;

  // 1) converts + y zero
  cvt_bf16_k<<<512, 256, 0, stream>>>(x,  xb,  BT * D_);
  cvt_bf16_k<<<512, 256, 0, stream>>>(Q,  Qb,  H_ * D_ * D_);
  cvt_bf16_k<<<512, 256, 0, stream>>>(P,  Pb,  H_ * D_ * D_);
  cvt_bf16_k<<<256, 256, 0, stream>>>(W1, W1b, 2 * D_ * D_);
  cvt_bf16_k<<<256, 256, 0, stream>>>(W2, W2b, 2 * D_ * D_);
  cvt_bf16_k<<<128, 256, 0, stream>>>(Wp, Wpb, D_ * D_);
  zfill_k  <<<512, 256, 0, stream>>>(yb, BT * D_);

  const float rsd = 1.f / sqrtf((float)D_);

  // 2) QZ[bh] = x[b] @ Q[h]^T   (z = bh, 16-way)
  gemm128<M_BF16><<<dim3(D_ / 128, T_ / 128, 16), 512, 0, stream>>>(
      xb, Qb, QZb, D_, D_, D_, D_, 1.f, nullptr, nullptr,
      (long)T_ * D_, 0L, 0L, (long)D_ * D_, (long)8 * T_ * D_, (long)T_ * D_, 0);

  // 3) PZt[bh] = (P[h] @ x[b]^T) / H   -> [e][s]
  gemm128<M_BF16><<<dim3(T_ / 128, D_ / 128, 16), 512, 0, stream>>>(
      Pb, xb, PZt, D_, D_, D_, T_, 1.f / H_, nullptr, nullptr,
      0L, (long)D_ * D_, (long)T_ * D_, 0L, (long)8 * D_ * T_, (long)D_ * T_, 0);

  // 4) per group-chunk, per row-strip: scores (causal) then y += scores @ PZt^T
  for (int g0 = 0; g0 < 16; g0 += nGrp) {
    const int b0 = g0 >> 3;
    const long sBhiS = (nGrp == 16) ? (long)T_ * D_ : 0L;       // xb batch stride
    const long sChiY = (nGrp == 16) ? (long)T_ * D_ : 0L;       // yb batch stride
    const long sAhiS = (long)8 * T_ * D_;                        // QZ hi stride (z>=8 only when nGrp=16)
    const long sBhiY = (long)8 * D_ * T_;                        // PZt hi stride
    for (int s0r = 0; s0r < T_; s0r += stripRows) {
      gemm128<M_SCORES><<<dim3(T_ / 128, stripRows / 128, nGrp), 512, 0, stream>>>(
          QZb + (size_t)g0 * T_ * D_ + (size_t)s0r * D_,
          xb + (size_t)b0 * T_ * D_, Sc,
          D_, D_, D_, T_, rsd, nullptr, nullptr,
          sAhiS, (long)T_ * D_,
          sBhiS, 0L,
          8 * scStride, scStride,
          s0r);
      gemm128<M_YACC><<<dim3(D_ / 128, stripRows / 128, nGrp), 512, 0, stream>>>(
          Sc, PZt + (size_t)g0 * D_ * T_,
          yb + (size_t)b0 * T_ * D_ + (size_t)s0r * D_,
          T_, T_, T_, D_, 1.f, nullptr, nullptr,
          8 * scStride, scStride,
          sBhiY, (long)D_ * T_,
          sChiY, 0L,
          s0r);
    }
  }

  // 5) z = LN(y + x) -> bf16   (into aliased QZb region)
  ln_k<<<BT, 256, 0, stream>>>(yb, x, gamma, beta, zb);

  // 6) MLP + residual + final projection
  gemm128<M_RELU><<<dim3(2 * D_ / 128, BT / 128, 1), 512, 0, stream>>>(
      zb, W1b, m1b, D_, D_, D_, 2 * D_, 1.f, b1, nullptr,
      0L, 0L, 0L, 0L, 0L, 0L, 0);
  gemm128<M_RES><<<dim3(D_ / 128, BT / 128, 1), 512, 0, stream>>>(
      m1b, W2b, z2b, 2 * D_, 2 * D_, 2 * D_, D_, 1.f, b2, zb,
      0L, 0L, 0L, 0L, 0L, 0L, 0);
  gemm128<M_F32B><<<dim3(D_ / 128, BT / 128, 1), 512, 0, stream>>>(
      z2b, Wpb, out, D_, D_, D_, D_, 1.f, bp, nullptr,
      0L, 0L, 0L, 0L, 0L, 0L, 0);
}

// Round 11
// 372.718 us; speedup vs baseline: 1.2702x; 1.0273x over previous
//
#include <hip/hip_runtime.h>
#include <hip/hip_bf16.h>
#include <cstdint>

#define DEV __device__ __forceinline__

typedef __attribute__((ext_vector_type(8))) short bf16x8;
typedef __attribute__((ext_vector_type(4))) float f32x4;

static constexpr int B_ = 2, T_ = 2048, D_ = 512, H_ = 8;

DEV ushort f2bf(float f) {
  union { float f; uint32_t u; } c; c.f = f;
  uint32_t u = c.u + 0x7fffu + ((c.u >> 16) & 1u);
  return (ushort)(u >> 16);
}
DEV float bf2f(ushort h) {
  union { uint32_t u; float f; } c; c.u = ((uint32_t)h) << 16; return c.f;
}

// async global->LDS, 16B per lane (LDS dest = wave-uniform base + lane*16)
DEV void gload16(const ushort* g, ushort* l) {
  __builtin_amdgcn_global_load_lds(
      (const __attribute__((address_space(1))) void*)g,
      (__attribute__((address_space(3))) void*)l, 16, 0, 0);
}

// fp32 -> bf16 (n % 4 == 0)
__global__ void cvt_bf16_k(const float* __restrict__ in, ushort* __restrict__ out, int n) {
  int stride = gridDim.x * blockDim.x;
  for (int i = blockIdx.x * blockDim.x + threadIdx.x; i * 4 < n; i += stride) {
    float4 f = reinterpret_cast<const float4*>(in)[i];
    ushort4 o;
    o.x = f2bf(f.x); o.y = f2bf(f.y); o.z = f2bf(f.z); o.w = f2bf(f.w);
    reinterpret_cast<ushort4*>(out)[i] = o;
  }
}

__global__ void zfill_k(float* __restrict__ p, int n) {  // n % 4 == 0
  int stride = gridDim.x * blockDim.x;
  for (int i = blockIdx.x * blockDim.x + threadIdx.x; i * 4 < n; i += stride)
    reinterpret_cast<float4*>(p)[i] = make_float4(0.f, 0.f, 0.f, 0.f);
}

enum { M_BF16 = 0, M_SCORES, M_YACC, M_RELU, M_RES, M_F32B };

// XCD-aware bijective block-id swizzle (m204): hw id orig -> logical wg so each
// XCD gets a contiguous logical range (neighbor tiles share L2-resident panels).
DEV void xcd_swz(int gx, int gy, int& bx, int& by) {
  const int n = gx * gy;
  const int orig = blockIdx.y * gx + blockIdx.x;
  const int q = n >> 3, r = n & 7;
  const int xcd = orig & 7, idx = orig >> 3;
  const int wg = (xcd < r ? xcd * (q + 1) : r * (q + 1) + (xcd - r) * q) + idx;
  bx = wg % gx; by = wg / gx;
}

// C = A (M x K, rm) * B^T (B stored N x K, rm), bf16 in, fp32 accum.
// 128x128 tile, BK=64 staged as TWO [128][32] k-halves (row stride 64B keeps
// ds_read_b128 at the 8-way conflict level; a single [128][64] would be 16-way),
// 8 waves (wave tile 64x32), global_load_lds width-16, 2-phase double-buffer
// prefetch, XCD-swizzled block ids.
// Batched over blockIdx.z: (z>>3, z&7) stride decomposition.
// rowBase: absolute row offset of A/C row 0 (causal logic in M_SCORES/M_YACC).
template<int MODE>
__global__ __launch_bounds__(512)
void gemm128(const ushort* __restrict__ Abase, const ushort* __restrict__ Bbase,
             void* __restrict__ Cbase, int K,
             int lda, int ldb, int ldc, float scale,
             const float* __restrict__ bias, const ushort* __restrict__ resid,
             long sAhi, long sAlo, long sBhi, long sBlo, long sChi, long sClo,
             int rowBase)
{
  constexpr int BM = 128, BN = 128, BK = 64;
  const int z = blockIdx.z;
  const int zhi = z >> 3, zlo = z & 7;
  const ushort* A = Abase + (long)zhi * sAhi + (long)zlo * sAlo;
  const ushort* B = Bbase + (long)zhi * sBhi + (long)zlo * sBlo;

  int bx, by;
  xcd_swz(gridDim.x, gridDim.y, bx, by);
  const int m0 = by * BM, n0 = bx * BN;
  if (MODE == M_SCORES && n0 > rowBase + m0 + (BM - 1)) return;  // fully-masked tile
  int kmax = K;
  if (MODE == M_YACC) kmax = min(K, rowBase + m0 + BM);          // causal K-limit

  // [dbuf][khalf][128][32] per array; 64KB total
  __shared__ ushort As[2][2 * 128 * 32], Bs[2][2 * 128 * 32];

  const int tid = threadIdx.x, lane = tid & 63, wave = tid >> 6;  // 8 waves
  const int wr = (wave >> 2) * 64, wc = (wave & 3) * 32;          // 2M x 4N wave grid
  const int fr = lane & 15, fg = lane >> 4;

  // staging: 512 threads cover one [128][32] half per gload: row = tid/4,
  // k-octet = tid%4; LDS elem off = tid*8 = row*32 + koct*8 (linear, byte=tid*16).
  const int srow = tid >> 2, sk = (tid & 3) * 8;
  const ushort* Ag = A + (long)(m0 + srow) * lda + sk;
  const ushort* Bg = B + (long)(n0 + srow) * ldb + sk;
  const int soff = tid * 8;  // byte off = tid*16 = wave*1024 + lane*16

  f32x4 acc[4][2] = {};

  const int nt = kmax / BK;  // kmax is a multiple of 64 in all uses
  // prologue: stage tile 0 (halves k+0 and k+32)
  gload16(Ag,      As[0] + soff);
  gload16(Ag + 32, As[0] + soff + 4096);
  gload16(Bg,      Bs[0] + soff);
  gload16(Bg + 32, Bs[0] + soff + 4096);
  __syncthreads();

  int cur = 0;
  for (int t = 0; t < nt; ++t) {
    // issue next-tile prefetch FIRST (stays in flight across ds_read+MFMA)
    if (t + 1 < nt) {
      const int kn = (t + 1) * BK;
      const int nb = cur ^ 1;
      gload16(Ag + kn,      As[nb] + soff);
      gload16(Ag + kn + 32, As[nb] + soff + 4096);
      gload16(Bg + kn,      Bs[nb] + soff);
      gload16(Bg + kn + 32, Bs[nb] + soff + 4096);
    }
    const ushort* Asc = As[cur];
    const ushort* Bsc = Bs[cur];
#pragma unroll
    for (int kk = 0; kk < 2; ++kk) {   // two 32-wide MFMA k-steps per staged tile
      const int hb = kk * 4096;        // k-half base
      bf16x8 a[4], b[2];
#pragma unroll
      for (int mi = 0; mi < 4; ++mi)
        a[mi] = *reinterpret_cast<const bf16x8*>(&Asc[hb + (wr + mi * 16 + fr) * 32 + fg * 8]);
#pragma unroll
      for (int ni = 0; ni < 2; ++ni)
        b[ni] = *reinterpret_cast<const bf16x8*>(&Bsc[hb + (wc + ni * 16 + fr) * 32 + fg * 8]);
#pragma unroll
      for (int mi = 0; mi < 4; ++mi)
#pragma unroll
        for (int ni = 0; ni < 2; ++ni)
          acc[mi][ni] = __builtin_amdgcn_mfma_f32_16x16x32_bf16(a[mi], b[ni], acc[mi][ni], 0, 0, 0);
    }
    __syncthreads();  // drains the in-flight prefetch (vmcnt(0)) AFTER compute
    cur ^= 1;
  }

  ushort* Cb = reinterpret_cast<ushort*>(Cbase);
  float*  Cf = reinterpret_cast<float*>(Cbase);
  const long coff = (long)zhi * sChi + (long)zlo * sClo;

#pragma unroll
  for (int mi = 0; mi < 4; ++mi)
#pragma unroll
    for (int ni = 0; ni < 2; ++ni) {
      int col = n0 + wc + ni * 16 + fr;
#pragma unroll
      for (int i = 0; i < 4; ++i) {
        int row = m0 + wr + mi * 16 + fg * 4 + i;   // C/D layout: col=lane&15, row=(lane>>4)*4+reg
        long idx = coff + (long)row * ldc + col;
        float v = acc[mi][ni][i];
        if (MODE == M_BF16)        { Cb[idx] = f2bf(v * scale); }
        else if (MODE == M_SCORES) { v *= scale; if (col > rowBase + row) v = 0.f; Cb[idx] = f2bf(v); }
        else if (MODE == M_YACC)   { atomicAdd(&Cf[idx], v); }
        else if (MODE == M_RELU)   { v += bias[col]; Cb[idx] = f2bf(fmaxf(v, 0.f)); }
        else if (MODE == M_RES)    { v += bias[col] + bf2f(resid[(long)row * ldc + col]); Cb[idx] = f2bf(v); }
        else                       { Cf[idx] = v + bias[col]; }
      }
    }
}

// LayerNorm(y + x) -> bf16; one block per row, D=512, 256 threads
__global__ __launch_bounds__(256)
void ln_k(const float* __restrict__ y, const float* __restrict__ x,
          const float* __restrict__ gamma, const float* __restrict__ beta,
          ushort* __restrict__ zb)
{
  const int r = blockIdx.x;
  const float* yr = y + (long)r * D_;
  const float* xr = x + (long)r * D_;
  int t = threadIdx.x;
  float v0 = yr[t] + xr[t];
  float v1 = yr[t + 256] + xr[t + 256];
  float s = v0 + v1, s2 = v0 * v0 + v1 * v1;
#pragma unroll
  for (int off = 1; off < 64; off <<= 1) {
    s  += __shfl_xor(s,  off);
    s2 += __shfl_xor(s2, off);
  }
  __shared__ float rs[4], rs2[4];
  int wave = t >> 6, lane = t & 63;
  if (lane == 0) { rs[wave] = s; rs2[wave] = s2; }
  __syncthreads();
  s  = rs[0] + rs[1] + rs[2] + rs[3];
  s2 = rs2[0] + rs2[1] + rs2[2] + rs2[3];
  float mean = s * (1.f / D_);
  float var  = s2 * (1.f / D_) - mean * mean;
  float rstd = rsqrtf(var + 1e-5f);
  zb[(long)r * D_ + t]       = f2bf((v0 - mean) * rstd * gamma[t] + beta[t]);
  zb[(long)r * D_ + t + 256] = f2bf((v1 - mean) * rstd * gamma[t + 256] + beta[t + 256]);
}

extern "C" void kernel_launch(void* const* d_in, const int* in_sizes, int n_in,
                              void* d_out, int out_size, void* d_ws, size_t ws_size,
                              hipStream_t stream)
{
  const float* x     = (const float*)d_in[0];
  const float* P     = (const float*)d_in[1];
  const float* Q     = (const float*)d_in[2];
  const float* gamma = (const float*)d_in[3];
  const float* beta  = (const float*)d_in[4];
  const float* W1    = (const float*)d_in[5];
  const float* b1    = (const float*)d_in[6];
  const float* W2    = (const float*)d_in[7];
  const float* b2    = (const float*)d_in[8];
  const float* Wp    = (const float*)d_in[9];
  const float* bp    = (const float*)d_in[10];
  float* out = (float*)d_out;

  char* ws = (char*)d_ws;
  size_t off = 0;
  auto alloc = [&](size_t bytes) -> char* {
    char* p = ws + off;
    off = (off + bytes + 255) & ~(size_t)255;
    return p;
  };
  const int BT = B_ * T_;  // 4096
  // Fixed allocations (~86.5 MB):
  ushort* xb  = (ushort*)alloc((size_t)BT * D_ * 2);
  ushort* Qb  = (ushort*)alloc((size_t)H_ * D_ * D_ * 2);
  ushort* Pb  = (ushort*)alloc((size_t)H_ * D_ * D_ * 2);
  ushort* W1b = (ushort*)alloc((size_t)2 * D_ * D_ * 2);
  ushort* W2b = (ushort*)alloc((size_t)2 * D_ * D_ * 2);
  ushort* Wpb = (ushort*)alloc((size_t)D_ * D_ * 2);
  ushort* QZb = (ushort*)alloc((size_t)B_ * H_ * T_ * D_ * 2);  // 33.5 MB
  ushort* PZt = (ushort*)alloc((size_t)B_ * H_ * D_ * T_ * 2);  // [bh][e][s]
  float*  yb  = (float*)alloc((size_t)BT * D_ * 4);
  // Aliased into QZb (dead after attention phase; stream order makes this safe):
  ushort* zb  = QZb;
  ushort* m1b = QZb + (size_t)BT * D_;
  ushort* z2b = QZb + (size_t)BT * D_ * 3;

  // Score buffer: nGrp group-buffers of stripRows x T bf16.
  size_t avail = ws_size > off ? ws_size - off : 0;
  int nGrp = 1, stripRows = 128;
  {
    const int cfgs[][2] = {{16,2048},{16,1024},{16,512},{16,256},{16,128},
                           {8,128},{4,128},{2,128},{1,128}};
    for (auto& c : cfgs) {
      if ((size_t)c[0] * c[1] * T_ * 2 <= avail) { nGrp = c[0]; stripRows = c[1]; break; }
    }
  }
  ushort* Sc = (ushort*)(ws + off);
  const long scStride = (long)stripRows * T_;

  // 1) converts + y zero
  cvt_bf16_k<<<512, 256, 0, stream>>>(x,  xb,  BT * D_);
  cvt_bf16_k<<<512, 256, 0, stream>>>(Q,  Qb,  H_ * D_ * D_);
  cvt_bf16_k<<<512, 256, 0, stream>>>(P,  Pb,  H_ * D_ * D_);
  cvt_bf16_k<<<256, 256, 0, stream>>>(W1, W1b, 2 * D_ * D_);
  cvt_bf16_k<<<256, 256, 0, stream>>>(W2, W2b, 2 * D_ * D_);
  cvt_bf16_k<<<128, 256, 0, stream>>>(Wp, Wpb, D_ * D_);
  zfill_k  <<<512, 256, 0, stream>>>(yb, BT * D_);

  const float rsd = 1.f / sqrtf((float)D_);

  // 2) QZ[bh] = x[b] @ Q[h]^T   (z = bh, 16-way)
  gemm128<M_BF16><<<dim3(D_ / 128, T_ / 128, 16), 512, 0, stream>>>(
      xb, Qb, QZb, D_, D_, D_, D_, 1.f, nullptr, nullptr,
      (long)T_ * D_, 0L, 0L, (long)D_ * D_, (long)8 * T_ * D_, (long)T_ * D_, 0);

  // 3) PZt[bh] = (P[h] @ x[b]^T) / H   -> [e][s]
  gemm128<M_BF16><<<dim3(T_ / 128, D_ / 128, 16), 512, 0, stream>>>(
      Pb, xb, PZt, D_, D_, D_, T_, 1.f / H_, nullptr, nullptr,
      0L, (long)D_ * D_, (long)T_ * D_, 0L, (long)8 * D_ * T_, (long)D_ * T_, 0);

  // 4) per group-chunk, per row-strip: scores (causal) then y += scores @ PZt^T
  for (int g0 = 0; g0 < 16; g0 += nGrp) {
    const int b0 = g0 >> 3;
    const long sBhiS = (nGrp == 16) ? (long)T_ * D_ : 0L;       // xb batch stride
    const long sChiY = (nGrp == 16) ? (long)T_ * D_ : 0L;       // yb batch stride
    const long sAhiS = (long)8 * T_ * D_;                        // QZ hi stride (z>=8 only when nGrp=16)
    const long sBhiY = (long)8 * D_ * T_;                        // PZt hi stride
    for (int s0r = 0; s0r < T_; s0r += stripRows) {
      gemm128<M_SCORES><<<dim3(T_ / 128, stripRows / 128, nGrp), 512, 0, stream>>>(
          QZb + (size_t)g0 * T_ * D_ + (size_t)s0r * D_,
          xb + (size_t)b0 * T_ * D_, Sc,
          D_, D_, D_, T_, rsd, nullptr, nullptr,
          sAhiS, (long)T_ * D_,
          sBhiS, 0L,
          8 * scStride, scStride,
          s0r);
      gemm128<M_YACC><<<dim3(D_ / 128, stripRows / 128, nGrp), 512, 0, stream>>>(
          Sc, PZt + (size_t)g0 * D_ * T_,
          yb + (size_t)b0 * T_ * D_ + (size_t)s0r * D_,
          T_, T_, T_, D_, 1.f, nullptr, nullptr,
          8 * scStride, scStride,
          sBhiY, (long)D_ * T_,
          sChiY, 0L,
          s0r);
    }
  }

  // 5) z = LN(y + x) -> bf16   (into aliased QZb region)
  ln_k<<<BT, 256, 0, stream>>>(yb, x, gamma, beta, zb);

  // 6) MLP + residual + final projection
  gemm128<M_RELU><<<dim3(2 * D_ / 128, BT / 128, 1), 512, 0, stream>>>(
      zb, W1b, m1b, D_, D_, D_, 2 * D_, 1.f, b1, nullptr,
      0L, 0L, 0L, 0L, 0L, 0L, 0);
  gemm128<M_RES><<<dim3(D_ / 128, BT / 128, 1), 512, 0, stream>>>(
      m1b, W2b, z2b, 2 * D_, 2 * D_, 2 * D_, D_, 1.f, b2, zb,
      0L, 0L, 0L, 0L, 0L, 0L, 0);
  gemm128<M_F32B><<<dim3(D_ / 128, BT / 128, 1), 512, 0, stream>>>(
      z2b, Wpb, out, D_, D_, D_, D_, 1.f, bp, nullptr,
      0L, 0L, 0L, 0L, 0L, 0L, 0);
}

// Round 14
// 364.493 us; speedup vs baseline: 1.2988x; 1.0226x over previous
//
#include <hip/hip_runtime.h>
#include <hip/hip_bf16.h>
#include <cstdint>

#define DEV __device__ __forceinline__

typedef __attribute__((ext_vector_type(8))) short bf16x8;
typedef __attribute__((ext_vector_type(4))) float f32x4;

static constexpr int B_ = 2, T_ = 2048, D_ = 512, H_ = 8;

DEV ushort f2bf(float f) {
  union { float f; uint32_t u; } c; c.f = f;
  uint32_t u = c.u + 0x7fffu + ((c.u >> 16) & 1u);
  return (ushort)(u >> 16);
}
DEV float bf2f(ushort h) {
  union { uint32_t u; float f; } c; c.u = ((uint32_t)h) << 16; return c.f;
}

// async global->LDS, 16B per lane (LDS dest = wave-uniform base + lane*16)
DEV void gload16(const ushort* g, ushort* l) {
  __builtin_amdgcn_global_load_lds(
      (const __attribute__((address_space(1))) void*)g,
      (__attribute__((address_space(3))) void*)l, 16, 0, 0);
}

// fp32 -> bf16 (n % 4 == 0)
__global__ void cvt_bf16_k(const float* __restrict__ in, ushort* __restrict__ out, int n) {
  int stride = gridDim.x * blockDim.x;
  for (int i = blockIdx.x * blockDim.x + threadIdx.x; i * 4 < n; i += stride) {
    float4 f = reinterpret_cast<const float4*>(in)[i];
    ushort4 o;
    o.x = f2bf(f.x); o.y = f2bf(f.y); o.z = f2bf(f.z); o.w = f2bf(f.w);
    reinterpret_cast<ushort4*>(out)[i] = o;
  }
}

__global__ void zfill_k(float* __restrict__ p, int n) {  // n % 4 == 0
  int stride = gridDim.x * blockDim.x;
  for (int i = blockIdx.x * blockDim.x + threadIdx.x; i * 4 < n; i += stride)
    reinterpret_cast<float4*>(p)[i] = make_float4(0.f, 0.f, 0.f, 0.f);
}

enum { M_BF16 = 0, M_SCORES, M_YACC, M_RELU, M_RES, M_F32B };

// XCD-aware bijective block-id swizzle (m204).
DEV void xcd_swz(int gx, int gy, int& bx, int& by) {
  const int n = gx * gy;
  const int orig = blockIdx.y * gx + blockIdx.x;
  const int q = n >> 3, r = n & 7;
  const int xcd = orig & 7, idx = orig >> 3;
  const int wg = (xcd < r ? xcd * (q + 1) : r * (q + 1) + (xcd - r) * q) + idx;
  bx = wg % gx; by = wg / gx;
}

// C = A (M x K, rm) * B^T (B stored N x K, rm), bf16 in, fp32 accum.
// 128x128 tile, BK=64 as two [128][32] k-halves, 8 waves (64x32 each),
// global_load_lds width-16, double-buffered with T4 COUNTED-vmcnt schedule:
// issue prefetch(t+1) -> s_waitcnt vmcnt(4) (tile-t landed; the 4 new loads
// STAY IN FLIGHT across the barrier) -> s_barrier -> ds_read+MFMA ->
// s_barrier (no drain). Never vmcnt(0) in the main loop (m218 pattern).
template<int MODE>
__global__ __launch_bounds__(512)
void gemm128(const ushort* __restrict__ Abase, const ushort* __restrict__ Bbase,
             void* __restrict__ Cbase, int K,
             int lda, int ldb, int ldc, float scale,
             const float* __restrict__ bias, const ushort* __restrict__ resid,
             long sAhi, long sAlo, long sBhi, long sBlo, long sChi, long sClo,
             int rowBase)
{
  constexpr int BM = 128, BN = 128, BK = 64;
  const int z = blockIdx.z;
  const int zhi = z >> 3, zlo = z & 7;
  const ushort* A = Abase + (long)zhi * sAhi + (long)zlo * sAlo;
  const ushort* B = Bbase + (long)zhi * sBhi + (long)zlo * sBlo;

  int bx, by;
  xcd_swz(gridDim.x, gridDim.y, bx, by);
  const int m0 = by * BM, n0 = bx * BN;
  if (MODE == M_SCORES && n0 > rowBase + m0 + (BM - 1)) return;  // fully-masked tile
  int kmax = K;
  if (MODE == M_YACC) kmax = min(K, rowBase + m0 + BM);          // causal K-limit

  // [dbuf][khalf][128][32] per array; 64KB total
  __shared__ ushort As[2][2 * 128 * 32], Bs[2][2 * 128 * 32];

  const int tid = threadIdx.x, lane = tid & 63, wave = tid >> 6;  // 8 waves
  const int wr = (wave >> 2) * 64, wc = (wave & 3) * 32;          // 2M x 4N wave grid
  const int fr = lane & 15, fg = lane >> 4;

  // staging: row = tid/4, k-octet = tid%4; LDS byte dest = tid*16 (uniform+lane*16)
  const int srow = tid >> 2, sk = (tid & 3) * 8;
  const ushort* Ag = A + (long)(m0 + srow) * lda + sk;
  const ushort* Bg = B + (long)(n0 + srow) * ldb + sk;
  const int soff = tid * 8;

  f32x4 acc[4][2] = {};

  const int nt = kmax / BK;  // multiple of 64 in all uses
  // prologue: stage tile 0 (no barrier here; first loop iter waits+syncs)
  gload16(Ag,      As[0] + soff);
  gload16(Ag + 32, As[0] + soff + 4096);
  gload16(Bg,      Bs[0] + soff);
  gload16(Bg + 32, Bs[0] + soff + 4096);

  int cur = 0;
  for (int t = 0; t < nt; ++t) {
    if (t + 1 < nt) {
      // issue next-tile prefetch, then wait only for tile-t (4 newest stay in flight)
      const int kn = (t + 1) * BK;
      const int nb = cur ^ 1;
      gload16(Ag + kn,      As[nb] + soff);
      gload16(Ag + kn + 32, As[nb] + soff + 4096);
      gload16(Bg + kn,      Bs[nb] + soff);
      gload16(Bg + kn + 32, Bs[nb] + soff + 4096);
      asm volatile("s_waitcnt vmcnt(4)" ::: "memory");
    } else {
      asm volatile("s_waitcnt vmcnt(0)" ::: "memory");
    }
    __builtin_amdgcn_s_barrier();   // everyone's tile-t staging visible

    const ushort* Asc = As[cur];
    const ushort* Bsc = Bs[cur];
#pragma unroll
    for (int kk = 0; kk < 2; ++kk) {   // two 32-wide MFMA k-steps per staged tile
      const int hb = kk * 4096;        // k-half base
      bf16x8 a[4], b[2];
#pragma unroll
      for (int mi = 0; mi < 4; ++mi)
        a[mi] = *reinterpret_cast<const bf16x8*>(&Asc[hb + (wr + mi * 16 + fr) * 32 + fg * 8]);
#pragma unroll
      for (int ni = 0; ni < 2; ++ni)
        b[ni] = *reinterpret_cast<const bf16x8*>(&Bsc[hb + (wc + ni * 16 + fr) * 32 + fg * 8]);
#pragma unroll
      for (int mi = 0; mi < 4; ++mi)
#pragma unroll
        for (int ni = 0; ni < 2; ++ni)
          acc[mi][ni] = __builtin_amdgcn_mfma_f32_16x16x32_bf16(a[mi], b[ni], acc[mi][ni], 0, 0, 0);
    }
    __builtin_amdgcn_s_barrier();   // all reads of buf[cur] done before overwrite
    cur ^= 1;
  }

  ushort* Cb = reinterpret_cast<ushort*>(Cbase);
  float*  Cf = reinterpret_cast<float*>(Cbase);
  const long coff = (long)zhi * sChi + (long)zlo * sClo;

#pragma unroll
  for (int mi = 0; mi < 4; ++mi)
#pragma unroll
    for (int ni = 0; ni < 2; ++ni) {
      int col = n0 + wc + ni * 16 + fr;
#pragma unroll
      for (int i = 0; i < 4; ++i) {
        int row = m0 + wr + mi * 16 + fg * 4 + i;   // C/D layout: col=lane&15, row=(lane>>4)*4+reg
        long idx = coff + (long)row * ldc + col;
        float v = acc[mi][ni][i];
        if (MODE == M_BF16)        { Cb[idx] = f2bf(v * scale); }
        else if (MODE == M_SCORES) { v *= scale; if (col > rowBase + row) v = 0.f; Cb[idx] = f2bf(v); }
        else if (MODE == M_YACC)   { atomicAdd(&Cf[idx], v); }
        else if (MODE == M_RELU)   { v += bias[col]; Cb[idx] = f2bf(fmaxf(v, 0.f)); }
        else if (MODE == M_RES)    { v += bias[col] + bf2f(resid[(long)row * ldc + col]); Cb[idx] = f2bf(v); }
        else                       { Cf[idx] = v + bias[col]; }
      }
    }
}

// LayerNorm(y + x) -> bf16; one block per row, D=512, 256 threads
__global__ __launch_bounds__(256)
void ln_k(const float* __restrict__ y, const float* __restrict__ x,
          const float* __restrict__ gamma, const float* __restrict__ beta,
          ushort* __restrict__ zb)
{
  const int r = blockIdx.x;
  const float* yr = y + (long)r * D_;
  const float* xr = x + (long)r * D_;
  int t = threadIdx.x;
  float v0 = yr[t] + xr[t];
  float v1 = yr[t + 256] + xr[t + 256];
  float s = v0 + v1, s2 = v0 * v0 + v1 * v1;
#pragma unroll
  for (int off = 1; off < 64; off <<= 1) {
    s  += __shfl_xor(s,  off);
    s2 += __shfl_xor(s2, off);
  }
  __shared__ float rs[4], rs2[4];
  int wave = t >> 6, lane = t & 63;
  if (lane == 0) { rs[wave] = s; rs2[wave] = s2; }
  __syncthreads();
  s  = rs[0] + rs[1] + rs[2] + rs[3];
  s2 = rs2[0] + rs2[1] + rs2[2] + rs2[3];
  float mean = s * (1.f / D_);
  float var  = s2 * (1.f / D_) - mean * mean;
  float rstd = rsqrtf(var + 1e-5f);
  zb[(long)r * D_ + t]       = f2bf((v0 - mean) * rstd * gamma[t] + beta[t]);
  zb[(long)r * D_ + t + 256] = f2bf((v1 - mean) * rstd * gamma[t + 256] + beta[t + 256]);
}

extern "C" void kernel_launch(void* const* d_in, const int* in_sizes, int n_in,
                              void* d_out, int out_size, void* d_ws, size_t ws_size,
                              hipStream_t stream)
{
  const float* x     = (const float*)d_in[0];
  const float* P     = (const float*)d_in[1];
  const float* Q     = (const float*)d_in[2];
  const float* gamma = (const float*)d_in[3];
  const float* beta  = (const float*)d_in[4];
  const float* W1    = (const float*)d_in[5];
  const float* b1    = (const float*)d_in[6];
  const float* W2    = (const float*)d_in[7];
  const float* b2    = (const float*)d_in[8];
  const float* Wp    = (const float*)d_in[9];
  const float* bp    = (const float*)d_in[10];
  float* out = (float*)d_out;

  char* ws = (char*)d_ws;
  size_t off = 0;
  auto alloc = [&](size_t bytes) -> char* {
    char* p = ws + off;
    off = (off + bytes + 255) & ~(size_t)255;
    return p;
  };
  const int BT = B_ * T_;  // 4096
  ushort* xb  = (ushort*)alloc((size_t)BT * D_ * 2);
  ushort* Qb  = (ushort*)alloc((size_t)H_ * D_ * D_ * 2);
  ushort* Pb  = (ushort*)alloc((size_t)H_ * D_ * D_ * 2);
  ushort* W1b = (ushort*)alloc((size_t)2 * D_ * D_ * 2);
  ushort* W2b = (ushort*)alloc((size_t)2 * D_ * D_ * 2);
  ushort* Wpb = (ushort*)alloc((size_t)D_ * D_ * 2);
  ushort* QZb = (ushort*)alloc((size_t)B_ * H_ * T_ * D_ * 2);  // 33.5 MB
  ushort* PZt = (ushort*)alloc((size_t)B_ * H_ * D_ * T_ * 2);  // [bh][e][s]
  float*  yb  = (float*)alloc((size_t)BT * D_ * 4);
  // Aliased into QZb (dead after attention phase):
  ushort* zb  = QZb;
  ushort* m1b = QZb + (size_t)BT * D_;
  ushort* z2b = QZb + (size_t)BT * D_ * 3;

  // Score buffer: nGrp group-buffers of stripRows x T bf16.
  size_t avail = ws_size > off ? ws_size - off : 0;
  int nGrp = 1, stripRows = 128;
  {
    const int cfgs[][2] = {{16,2048},{16,1024},{16,512},{16,256},{16,128},
                           {8,128},{4,128},{2,128},{1,128}};
    for (auto& c : cfgs) {
      if ((size_t)c[0] * c[1] * T_ * 2 <= avail) { nGrp = c[0]; stripRows = c[1]; break; }
    }
  }
  ushort* Sc = (ushort*)(ws + off);
  const long scStride = (long)stripRows * T_;

  // 1) converts + y zero
  cvt_bf16_k<<<512, 256, 0, stream>>>(x,  xb,  BT * D_);
  cvt_bf16_k<<<512, 256, 0, stream>>>(Q,  Qb,  H_ * D_ * D_);
  cvt_bf16_k<<<512, 256, 0, stream>>>(P,  Pb,  H_ * D_ * D_);
  cvt_bf16_k<<<256, 256, 0, stream>>>(W1, W1b, 2 * D_ * D_);
  cvt_bf16_k<<<256, 256, 0, stream>>>(W2, W2b, 2 * D_ * D_);
  cvt_bf16_k<<<128, 256, 0, stream>>>(Wp, Wpb, D_ * D_);
  zfill_k  <<<512, 256, 0, stream>>>(yb, BT * D_);

  const float rsd = 1.f / sqrtf((float)D_);

  // 2) QZ[bh] = x[b] @ Q[h]^T   (z = bh, 16-way)
  gemm128<M_BF16><<<dim3(D_ / 128, T_ / 128, 16), 512, 0, stream>>>(
      xb, Qb, QZb, D_, D_, D_, D_, 1.f, nullptr, nullptr,
      (long)T_ * D_, 0L, 0L, (long)D_ * D_, (long)8 * T_ * D_, (long)T_ * D_, 0);

  // 3) PZt[bh] = (P[h] @ x[b]^T) / H   -> [e][s]
  gemm128<M_BF16><<<dim3(T_ / 128, D_ / 128, 16), 512, 0, stream>>>(
      Pb, xb, PZt, D_, D_, D_, T_, 1.f / H_, nullptr, nullptr,
      0L, (long)D_ * D_, (long)T_ * D_, 0L, (long)8 * D_ * T_, (long)D_ * T_, 0);

  // 4) per group-chunk, per row-strip: scores (causal) then y += scores @ PZt^T
  for (int g0 = 0; g0 < 16; g0 += nGrp) {
    const int b0 = g0 >> 3;
    const long sBhiS = (nGrp == 16) ? (long)T_ * D_ : 0L;
    const long sChiY = (nGrp == 16) ? (long)T_ * D_ : 0L;
    const long sAhiS = (long)8 * T_ * D_;
    const long sBhiY = (long)8 * D_ * T_;
    for (int s0r = 0; s0r < T_; s0r += stripRows) {
      gemm128<M_SCORES><<<dim3(T_ / 128, stripRows / 128, nGrp), 512, 0, stream>>>(
          QZb + (size_t)g0 * T_ * D_ + (size_t)s0r * D_,
          xb + (size_t)b0 * T_ * D_, Sc,
          D_, D_, D_, T_, rsd, nullptr, nullptr,
          sAhiS, (long)T_ * D_,
          sBhiS, 0L,
          8 * scStride, scStride,
          s0r);
      gemm128<M_YACC><<<dim3(D_ / 128, stripRows / 128, nGrp), 512, 0, stream>>>(
          Sc, PZt + (size_t)g0 * D_ * T_,
          yb + (size_t)b0 * T_ * D_ + (size_t)s0r * D_,
          T_, T_, T_, D_, 1.f, nullptr, nullptr,
          8 * scStride, scStride,
          sBhiY, (long)D_ * T_,
          sChiY, 0L,
          s0r);
    }
  }

  // 5) z = LN(y + x) -> bf16   (into aliased QZb region)
  ln_k<<<BT, 256, 0, stream>>>(yb, x, gamma, beta, zb);

  // 6) MLP + residual + final projection
  gemm128<M_RELU><<<dim3(2 * D_ / 128, BT / 128, 1), 512, 0, stream>>>(
      zb, W1b, m1b, D_, D_, D_, 2 * D_, 1.f, b1, nullptr,
      0L, 0L, 0L, 0L, 0L, 0L, 0);
  gemm128<M_RES><<<dim3(D_ / 128, BT / 128, 1), 512, 0, stream>>>(
      m1b, W2b, z2b, 2 * D_, 2 * D_, 2 * D_, D_, 1.f, b2, zb,
      0L, 0L, 0L, 0L, 0L, 0L, 0);
  gemm128<M_F32B><<<dim3(D_ / 128, BT / 128, 1), 512, 0, stream>>>(
      z2b, Wpb, out, D_, D_, D_, D_, 1.f, bp, nullptr,
      0L, 0L, 0L, 0L, 0L, 0L, 0);
}